// Round 9
// baseline (277.775 us; speedup 1.0000x reference)
//
#include <hip/hip_runtime.h>
#include <stdint.h>

#define NHEADS 32
#define DHEAD  128
#define LQ     2048
#define PAGE   16
#define QTILE  64     // q rows per q-tile (4 waves x 16)
#define NQT    32     // q-tiles total (LQ/QTILE)
#define KVB    32     // kv tokens per tile (= 2 pages)
#define KPAD   136    // 128 + 8 f16 pad

typedef _Float16 f16x8 __attribute__((ext_vector_type(8)));
typedef _Float16 f16x2v __attribute__((ext_vector_type(2)));
typedef float    f32x4 __attribute__((ext_vector_type(4)));

__global__ __launch_bounds__(256, 2)
void paged_attn_kernel(const float* __restrict__ q,
                       const int*   __restrict__ Kp,      // int8 widened to int32
                       const int*   __restrict__ Vp,      // int8 widened to int32
                       const float* __restrict__ Kscale,  // f16 widened to f32
                       const float* __restrict__ Vscale,
                       const int*   __restrict__ pages,
                       float* __restrict__ out)
{
    __shared__ _Float16 Ks[2][KVB][KPAD];                 // double-buffered K tile
    __shared__ __align__(16) _Float16 Vt[2][DHEAD][KVB];  // double-buffered V^T (swizzled)

    const int tid  = threadIdx.x;
    const int w    = tid >> 6;
    const int lane = tid & 63;
    const int g    = lane >> 4;       // 0..3
    const int c    = lane & 15;       // 0..15

    const int bx = blockIdx.x;
    const int h  = bx & (NHEADS - 1);
    const int p  = bx >> 5;                  // pair id 0..15
    const int qa = p, qb = NQT - 1 - p;      // balanced causal pair
    const int q0a = qa * QTILE, q0b = qb * QTILE;

    const float qscale = 0.08838834764831845f * 1.44269504088896340736f;

    // ---- Q fragments (A/B-layout: row/col = lane&15, k = (lane>>4)*8+i) ----
    f16x8 qfa[4], qfb[4];
    {
        const float* qpa = q + ((size_t)h * LQ + q0a + w * 16 + c) * DHEAD;
        const float* qpb = q + ((size_t)h * LQ + q0b + w * 16 + c) * DHEAD;
        #pragma unroll
        for (int t = 0; t < 4; ++t)
            #pragma unroll
            for (int i = 0; i < 8; ++i) {
                qfa[t][i] = (_Float16)(qpa[t * 32 + g * 8 + i] * qscale);
                qfb[t][i] = (_Float16)(qpb[t * 32 + g * 8 + i] * qscale);
            }
    }

    f32x4 oaccA[8], oaccB[8];
    #pragma unroll
    for (int d = 0; d < 8; ++d) { oaccA[d] = (f32x4){0,0,0,0}; oaccB[d] = (f32x4){0,0,0,0}; }
    float mA = -1e30f, lA = 0.f, mB = -1e30f, lB = 0.f;

    const int ntiles = 2 * qb + 2;
    const int skv = tid >> 3;                // staging kv row 0..31
    const int sa  = tid & 7;                 // staging d-chunk 0..7

    auto issue = [&](int tile, int4* krD, int4* vrD, float& ksD, float& vsD) {
        const int t_glob = tile * KVB + skv;
        const int pg  = pages[t_glob >> 4];
        const int tok = t_glob & 15;
        const size_t base = (((size_t)pg * PAGE + tok) * NHEADS + h) * DHEAD + sa * 16;
        const int4* kp4 = (const int4*)(Kp + base);
        const int4* vp4 = (const int4*)(Vp + base);
        #pragma unroll
        for (int j = 0; j < 4; ++j) { krD[j] = kp4[j]; vrD[j] = vp4[j]; }
        ksD = Kscale[pg * NHEADS + h];
        vsD = Vscale[pg * NHEADS + h];
    };

    auto stage = [&](int b, const int4* kr4, const int4* vr4, float ksr, float vsr) {
        const int* ki = (const int*)kr4;
        const int* vi = (const int*)vr4;
        f16x8 klo, khi;
        #pragma unroll
        for (int i = 0; i < 8; ++i) {
            klo[i] = (_Float16)((float)ki[i]     * ksr);
            khi[i] = (_Float16)((float)ki[8 + i] * ksr);
        }
        *(f16x8*)&Ks[b][skv][sa * 16]     = klo;
        *(f16x8*)&Ks[b][skv][sa * 16 + 8] = khi;
        char* vtb = (char*)&Vt[b][0][0];
        #pragma unroll
        for (int j = 0; j < 16; ++j) {
            const int dcol = sa * 16 + j;
            unsigned off = (unsigned)(dcol * (KVB * 2) + skv * 2);
            off ^= (unsigned)(((dcol >> 3) & 7) << 4);
            *(_Float16*)(vtb + off) = (_Float16)((float)vi[j] * vsr);
        }
    };

    // Swapped-QK^T compute: lane holds S[q=qW+c][kv=kv0+16nt+4g+r]. kf/vf hoisted+shared.
    auto compute = [&](int kv0, const f16x8 (*kf)[4], const f16x8* vf,
                       const f16x8* qf, int q0t, f32x4* oacc, float& mr, float& lr) {
        f32x4 s0 = (f32x4){0,0,0,0}, s1 = (f32x4){0,0,0,0};
        #pragma unroll
        for (int t = 0; t < 4; ++t) {
            s0 = __builtin_amdgcn_mfma_f32_16x16x32_f16(kf[0][t], qf[t], s0, 0, 0, 0);
            s1 = __builtin_amdgcn_mfma_f32_16x16x32_f16(kf[1][t], qf[t], s1, 0, 0, 0);
        }
        // causal mask: kv = kv0 + 16*nt + 4g + r  >  q = q0t + w*16 + c -> masked
        const int dq = (q0t + w * 16 + c) - (kv0 + 4 * g);
        #pragma unroll
        for (int r = 0; r < 4; ++r) {
            if (r > dq)      s0[r] = -1e30f;
            if (r > dq - 16) s1[r] = -1e30f;
        }
        float tm = fmaxf(fmaxf(fmaxf(s0[0], s0[1]), fmaxf(s0[2], s0[3])),
                         fmaxf(fmaxf(s1[0], s1[1]), fmaxf(s1[2], s1[3])));
        tm = fmaxf(tm, __shfl_xor(tm, 16, 64));
        tm = fmaxf(tm, __shfl_xor(tm, 32, 64));
        const float mn    = fmaxf(mr, tm);
        const float alpha = exp2f(mr - mn);
        mr = mn;
        float p0[4], p1[4];
        #pragma unroll
        for (int r = 0; r < 4; ++r) {
            p0[r] = exp2f(s0[r] - mn);
            p1[r] = exp2f(s1[r] - mn);
        }
        float rs = ((p0[0] + p0[1]) + (p0[2] + p0[3])) +
                   ((p1[0] + p1[1]) + (p1[2] + p1[3]));
        rs += __shfl_xor(rs, 16, 64);
        rs += __shfl_xor(rs, 32, 64);
        lr = lr * alpha + rs;
        // alpha for o_acc rows q=4g+r lives in lane 20g+r
        float aR[4];
        #pragma unroll
        for (int r = 0; r < 4; ++r) aR[r] = __shfl(alpha, 20 * g + r, 64);
        #pragma unroll
        for (int d = 0; d < 8; ++d)
            #pragma unroll
            for (int r = 0; r < 4; ++r)
                oacc[d][r] *= aR[r];
        // ---- P redistribution to PV A-frag (in-register; see R7 derivation) ----
        f16x2v t0, t1, t2, t3;
        t0[0] = (_Float16)p0[0]; t0[1] = (_Float16)p0[1];
        t1[0] = (_Float16)p0[2]; t1[1] = (_Float16)p0[3];
        t2[0] = (_Float16)p1[0]; t2[1] = (_Float16)p1[1];
        t3[0] = (_Float16)p1[2]; t3[1] = (_Float16)p1[3];
        const int w00 = __builtin_bit_cast(int, t0);
        const int w01 = __builtin_bit_cast(int, t1);
        const int w10 = __builtin_bit_cast(int, t2);
        const int w11 = __builtin_bit_cast(int, t3);
        const int srcL = ((g & 1) << 5) | c;
        const int srcH = srcL + 16;
        const int e0A = __shfl(w00, srcL, 64), e0B = __shfl(w10, srcL, 64);
        const int e1A = __shfl(w01, srcL, 64), e1B = __shfl(w11, srcL, 64);
        const int e2A = __shfl(w00, srcH, 64), e2B = __shfl(w10, srcH, 64);
        const int e3A = __shfl(w01, srcH, 64), e3B = __shfl(w11, srcH, 64);
        const bool hi = g >= 2;
        uint4 aw;
        aw.x = (unsigned)(hi ? e0B : e0A);
        aw.y = (unsigned)(hi ? e1B : e1A);
        aw.z = (unsigned)(hi ? e2B : e2A);
        aw.w = (unsigned)(hi ? e3B : e3A);
        const f16x8 pa = __builtin_bit_cast(f16x8, aw);
        // ---- PV from hoisted vf regs ----
        #pragma unroll
        for (int d = 0; d < 8; ++d)
            oacc[d] = __builtin_amdgcn_mfma_f32_16x16x32_f16(pa, vf[d], oacc[d], 0, 0, 0);
    };

    // ---- prologue: fill buffer 0, prefetch tile 1 ----
    int4 krB[4], vrB[4]; float ksrB = 0.f, vsrB = 0.f;
    issue(0, krB, vrB, ksrB, vsrB);
    stage(0, krB, vrB, ksrB, vsrB);
    if (ntiles > 1) issue(1, krB, vrB, ksrB, vsrB);
    __syncthreads();

    for (int t = 0; t < ntiles; ++t) {
        const int b   = t & 1;
        const int kv0 = t * KVB;

        // hoisted K and V fragments (shared by both paired computes)
        f16x8 kf[2][4], vf[8];
        #pragma unroll
        for (int tt = 0; tt < 4; ++tt) {
            kf[0][tt] = *(const f16x8*)&Ks[b][c][tt * 32 + g * 8];
            kf[1][tt] = *(const f16x8*)&Ks[b][16 + c][tt * 32 + g * 8];
        }
        const char* vtb = (const char*)&Vt[b][0][0];
        #pragma unroll
        for (int d = 0; d < 8; ++d) {
            const int dcol = d * 16 + c;
            unsigned off = (unsigned)(dcol * (KVB * 2) + g * 16);
            off ^= (unsigned)(((dcol >> 3) & 7) << 4);
            vf[d] = *(const f16x8*)(vtb + off);
        }

        if (kv0 <= q0b + w * 16 + 15)
            compute(kv0, kf, vf, qfb, q0b, oaccB, mB, lB);
        if (kv0 <= q0a + w * 16 + 15)
            compute(kv0, kf, vf, qfa, q0a, oaccA, mA, lA);

        // stage next tile into the other buffer (overlaps other waves' compute),
        // then prefetch tile t+2 (full tile of latency cover)
        if (t + 1 < ntiles) {
            stage((t + 1) & 1, krB, vrB, ksrB, vsrB);
            if (t + 2 < ntiles) issue(t + 2, krB, vrB, ksrB, vsrB);
        }
        __syncthreads();   // single barrier per tile
    }

    // ---- normalize + store (l for row q=4g+r lives in lane 20g+r) ----
    float iA[4], iB[4];
    #pragma unroll
    for (int r = 0; r < 4; ++r) {
        iA[r] = 1.f / __shfl(lA, 20 * g + r, 64);
        iB[r] = 1.f / __shfl(lB, 20 * g + r, 64);
    }
    const int qgA = q0a + w * 16 + g * 4;
    const int qgB = q0b + w * 16 + g * 4;
    #pragma unroll
    for (int d = 0; d < 8; ++d)
        #pragma unroll
        for (int r = 0; r < 4; ++r) {
            out[((size_t)h * LQ + qgA + r) * DHEAD + d * 16 + c] = oaccA[d][r] * iA[r];
            out[((size_t)h * LQ + qgB + r) * DHEAD + d * 16 + c] = oaccB[d][r] * iB[r];
        }
}

extern "C" void kernel_launch(void* const* d_in, const int* in_sizes, int n_in,
                              void* d_out, int out_size, void* d_ws, size_t ws_size,
                              hipStream_t stream) {
    (void)in_sizes; (void)n_in; (void)d_ws; (void)ws_size; (void)out_size;
    const float* qp = (const float*)d_in[0];
    const int*   kp = (const int*)d_in[1];    // int8 -> int32 per harness contract
    const int*   vp = (const int*)d_in[2];
    const float* ks = (const float*)d_in[3];  // f16 -> f32 per harness contract
    const float* vs = (const float*)d_in[4];
    const int*   pg = (const int*)d_in[5];
    float*       op = (float*)d_out;

    dim3 grid(NHEADS * (NQT / 2));   // 512 balanced pair-blocks
    dim3 block(256);
    paged_attn_kernel<<<grid, block, 0, stream>>>(qp, kp, vp, ks, vs, pg, op);
}